// Round 1
// baseline (75.518 us; speedup 1.0000x reference)
//
#include <hip/hip_runtime.h>
#include <math.h>

#define RADIUS 5
#define DIAM   11

constexpr int TILE = 16;
constexpr int LT   = TILE + 2 * RADIUS;  // 26
constexpr int NOFF = 60;                 // positive offsets: (0,1..5), (1..5, -5..5)
constexpr int HALF_OFF = 30;

// ---- compile-time spatial weight table -------------------------------------
// exp(x) for x in [-0.695, 0): Taylor to 22 terms -> exact at double precision.
constexpr double cexp_small(double x) {
    double s = 1.0, t = 1.0;
    for (int i = 1; i <= 22; ++i) { t *= x / (double)i; s += t; }
    return s;
}

struct WTab { float c1[NOFF]; float c2[NOFF]; };

constexpr WTab make_wtab() {
    WTab w{};
    for (int k = 0; k < NOFF; ++k) {
        int di, dj;
        if (k < 5) { di = 0; dj = k + 1; }
        else       { di = (k - 5) / DIAM + 1; dj = (k - 5) % DIAM - RADIUS; }
        double e = cexp_small(-(double)(di * di + dj * dj) / 72.0);
        w.c1[k] = (float)(0.9 * e);   // 0.9 * exp(-(di^2+dj^2)/72)
        w.c2[k] = (float)(0.1 * e);   // 0.1 * exp(-(di^2+dj^2)/72)
    }
    return w;
}

constexpr WTab WT = make_wtab();

// Binarize per reference: NaN -> 0, <1 -> 0, else keep value
__device__ __forceinline__ float binarize(float v) {
    return (isnan(v) || v < 1.0f) ? 0.0f : v;
}

// Accumulate 30 of the 60 positive offsets (compile-time range -> full fold).
template<int K0>
__device__ __forceinline__ float accum_half(
    const float4 (*sP)[LT], const float2 (*sM)[LT],
    int ci, int cj, float4 C, float2 Mc)
{
    const float sc   = C.w;
    const float c1m2 = 1.0f - 2.0f * sc;     // (1-sim) = fma(a, 1-2b, b)
    float lsum = 0.0f;
    #pragma unroll
    for (int k = K0; k < K0 + HALF_OFF; ++k) {
        int di, dj;   // constant-folded under full unroll
        if (k < 5) { di = 0; dj = k + 1; }
        else       { di = (k - 5) / DIAM + 1; dj = (k - 5) % DIAM - RADIUS; }
        const float4 P = sP[ci + di][cj + dj];
        const float2 M = sM[ci + di][cj + dj];
        float d0 = P.x - C.x, d1 = P.y - C.y, d2 = P.z - C.z;
        float u  = fmaf(d2, d2, fmaf(d1, d1, d0 * d0));
        float e  = __expf(-50.0f * u);
        float w  = fmaf(WT.c1[k], e, WT.c2[k]);    // literal weights, no LDS
        float oms = fmaf(P.w, c1m2, sc);           // 1 - sim
        float pm  = fmaf(Mc.x, M.y, M.x * Mc.y);   // ms_c*md_q + ms_q*md_c
        lsum = fmaf(w * oms, pm, lsum);
    }
    return lsum;
}

// Pair-symmetric formulation:
//   numerator = sum over unordered pairs {p,q=p+t}, t positive offset, of
//       w(p,q) * (1 - sim(p,q)) * (ms_q*md_p + ms_p*md_q)
//   denominator = sum of binarized md
// Block = 16x16 pixels x 2 offset-halves (512 threads, 8 waves):
//   halo loaded ONCE per block; each half covers 30 offsets -> 2x occupancy.
__global__ __launch_bounds__(512, 4) void crf_main(
    const float* __restrict__ x,      // [N,3,H,W]
    const float* __restrict__ y,      // [N,H,W]
    const float* __restrict__ msrc,   // [N,1,H,W]
    const float* __restrict__ mdst,   // [N,1,H,W]
    float2* __restrict__ partial,     // [gridX*gridY*N]
    int H, int W)
{
    __shared__ float4 sP[LT][LT];   // x0,x1,x2,sigmoid(y)
    __shared__ float2 sM[LT][LT];   // binarized ms, binarized md
    __shared__ float  wRedA[8], wRedB[8];

    const int n   = blockIdx.z;
    const int ti0 = blockIdx.y * TILE;
    const int tj0 = blockIdx.x * TILE;
    const int tid = (threadIdx.z * TILE + threadIdx.y) * TILE + threadIdx.x;

    const long long planeHW = (long long)H * W;
    const float* xn  = x    + (long long)n * 3 * planeHW;
    const float* yn  = y    + (long long)n * planeHW;
    const float* msn = msrc + (long long)n * planeHW;
    const float* mdn = mdst + (long long)n * planeHW;

    // cooperative halo load (676 elems / 512 threads)
    for (int idx = tid; idx < LT * LT; idx += 512) {
        int li = idx / LT, lj = idx % LT;
        int gi = ti0 - RADIUS + li;
        int gj = tj0 - RADIUS + lj;
        float4 P = make_float4(0.f, 0.f, 0.f, 0.f);
        float2 M = make_float2(0.f, 0.f);
        if (gi >= 0 && gi < H && gj >= 0 && gj < W) {
            long long p = (long long)gi * W + gj;
            P.x = xn[p];
            P.y = xn[planeHW + p];
            P.z = xn[2 * planeHW + p];
            P.w = 1.0f / (1.0f + __expf(-yn[p]));
            M.x = binarize(msn[p]);
            M.y = binarize(mdn[p]);
        }
        sP[li][lj] = P;
        sM[li][lj] = M;
    }
    __syncthreads();

    const int ci = threadIdx.y + RADIUS, cj = threadIdx.x + RADIUS;
    const int gi = ti0 + threadIdx.y,    gj = tj0 + threadIdx.x;
    const bool valid = (gi < H && gj < W);

    float lsum = 0.0f, mdb = 0.0f;
    if (valid) {
        const float4 C  = sP[ci][cj];
        const float2 Mc = sM[ci][cj];
        if (threadIdx.z == 0) {           // wave-uniform branch (z is per-256-chunk)
            lsum = accum_half<0>(sP, sM, ci, cj, C, Mc);
            mdb  = Mc.y;                  // denominator counted once per pixel
        } else {
            lsum = accum_half<HALF_OFF>(sP, sM, ci, cj, C, Mc);
        }
    }

    // block reduction: wave shuffle then 8 partials in LDS
    float a = lsum, b = mdb;
    #pragma unroll
    for (int off = 32; off > 0; off >>= 1) {
        a += __shfl_down(a, off, 64);
        b += __shfl_down(b, off, 64);
    }
    const int wave = tid >> 6, lane = tid & 63;
    if (lane == 0) { wRedA[wave] = a; wRedB[wave] = b; }
    __syncthreads();
    if (tid == 0) {
        float t1 = 0.f, t2 = 0.f;
        #pragma unroll
        for (int wv = 0; wv < 8; ++wv) { t1 += wRedA[wv]; t2 += wRedB[wv]; }
        int bid = (blockIdx.z * gridDim.y + blockIdx.y) * gridDim.x + blockIdx.x;
        partial[bid] = make_float2(t1, t2);   // plain store: no init needed
    }
}

__global__ __launch_bounds__(256) void crf_final(
    const float2* __restrict__ partial, int G, float* __restrict__ out)
{
    __shared__ float wRedA[4], wRedB[4];
    float a = 0.f, b = 0.f;
    for (int i = threadIdx.x; i < G; i += 256) {
        float2 p = partial[i];
        a += p.x; b += p.y;
    }
    #pragma unroll
    for (int off = 32; off > 0; off >>= 1) {
        a += __shfl_down(a, off, 64);
        b += __shfl_down(b, off, 64);
    }
    const int wave = threadIdx.x >> 6, lane = threadIdx.x & 63;
    if (lane == 0) { wRedA[wave] = a; wRedB[wave] = b; }
    __syncthreads();
    if (threadIdx.x == 0) {
        double num   = (double)wRedA[0] + wRedA[1] + wRedA[2] + wRedA[3];
        double denom = (double)wRedB[0] + wRedB[1] + wRedB[2] + wRedB[3];
        if (denom < 1.0) denom = 1.0;
        out[0] = (float)(num / denom);
    }
}

extern "C" void kernel_launch(void* const* d_in, const int* in_sizes, int n_in,
                              void* d_out, int out_size, void* d_ws, size_t ws_size,
                              hipStream_t stream) {
    const float* x  = (const float*)d_in[0];
    const float* yv = (const float*)d_in[1];
    const float* ms = (const float*)d_in[2];
    const float* md = (const float*)d_in[3];
    float* out      = (float*)d_out;
    float2* partial = (float2*)d_ws;

    const int H = 256, W = 256;
    const int N = in_sizes[1] / (H * W);  // y is [N,H,W]

    dim3 block(TILE, TILE, 2);
    dim3 grid((W + TILE - 1) / TILE, (H + TILE - 1) / TILE, N);
    const int G = grid.x * grid.y * grid.z;

    hipLaunchKernelGGL(crf_main, grid, block, 0, stream, x, yv, ms, md, partial, H, W);
    hipLaunchKernelGGL(crf_final, dim3(1), dim3(256), 0, stream, partial, G, out);
}

// Round 2
// 69.152 us; speedup vs baseline: 1.0921x; 1.0921x over previous
//
#include <hip/hip_runtime.h>
#include <math.h>

#define RADIUS 5
#define DIAM   11

constexpr int TILE = 16;
constexpr int LT   = TILE + 2 * RADIUS;  // 26
constexpr int NOFF = 60;                 // positive offsets: (0,1..5), (1..5, -5..5)

// ---- compile-time spatial weight table -------------------------------------
// exp(x) for x in [-0.695, 0): Taylor to 22 terms -> exact at double precision.
constexpr double cexp_small(double x) {
    double s = 1.0, t = 1.0;
    for (int i = 1; i <= 22; ++i) { t *= x / (double)i; s += t; }
    return s;
}

struct WTab { float c1[NOFF]; float c2[NOFF]; };

constexpr WTab make_wtab() {
    WTab w{};
    for (int k = 0; k < NOFF; ++k) {
        int di, dj;
        if (k < 5) { di = 0; dj = k + 1; }
        else       { di = (k - 5) / DIAM + 1; dj = (k - 5) % DIAM - RADIUS; }
        double e = cexp_small(-(double)(di * di + dj * dj) / 72.0);
        w.c1[k] = (float)(0.9 * e);   // 0.9 * exp(-(di^2+dj^2)/72)
        w.c2[k] = (float)(0.1 * e);   // 0.1 * exp(-(di^2+dj^2)/72)
    }
    return w;
}

constexpr WTab WT = make_wtab();

// Binarize per reference: NaN -> 0, <1 -> 0, else keep value
__device__ __forceinline__ float binarize(float v) {
    return (isnan(v) || v < 1.0f) ? 0.0f : v;
}

// Pair-symmetric formulation:
//   numerator = sum over unordered pairs {p,q=p+t}, t positive offset, of
//       w(p,q) * (1 - sim(p,q)) * (ms_q*md_p + ms_p*md_q)
//   w = exp(-(di^2+dj^2)/72) * (0.9*exp(-50*|x_q-x_p|^2) + 0.1)
//   1 - sim = a + b - 2ab   (a=sig_q, b=sig_p)
//   denominator = sum of binarized md
// Round-2 structure: 256 threads, one pixel + all 60 offsets per thread
// (round-0 proven; 512-thread offset-split regressed 3x: VGPR=64 killed
//  LDS-read pipelining). Spatial weights are compile-time literals (no LDS
//  table: -60 ds_read_b32/pixel = -1/3 of loop LDS instructions). Halo
//  loads are unconditional clamped + select-zero so all 18 issue branch-free.
__global__ __launch_bounds__(256) void crf_main(
    const float* __restrict__ x,      // [N,3,H,W]
    const float* __restrict__ y,      // [N,H,W]
    const float* __restrict__ msrc,   // [N,1,H,W]
    const float* __restrict__ mdst,   // [N,1,H,W]
    float2* __restrict__ partial,     // [gridX*gridY*N]
    int H, int W)
{
    __shared__ float4 sP[LT][LT];   // x0,x1,x2,sigmoid(y)
    __shared__ float2 sM[LT][LT];   // binarized ms, binarized md
    __shared__ float  wRedA[4], wRedB[4];

    const int n   = blockIdx.z;
    const int ti0 = blockIdx.y * TILE;
    const int tj0 = blockIdx.x * TILE;
    const int tid = threadIdx.y * TILE + threadIdx.x;

    const long long planeHW = (long long)H * W;
    const float* xn  = x    + (long long)n * 3 * planeHW;
    const float* yn  = y    + (long long)n * planeHW;
    const float* msn = msrc + (long long)n * planeHW;
    const float* mdn = mdst + (long long)n * planeHW;

    // cooperative halo load: 676 elems / 256 threads = 3 predicated rounds.
    // All global loads unconditional (clamped addresses) so the compiler can
    // issue all 18 up front; OOB lanes select zero before the LDS write.
    #pragma unroll
    for (int it = 0; it < 3; ++it) {
        const int idx  = tid + it * 256;
        const bool act = (idx < LT * LT);
        const int cidx = act ? idx : (LT * LT - 1);
        const int li = cidx / LT, lj = cidx % LT;
        const int gi = ti0 - RADIUS + li;
        const int gj = tj0 - RADIUS + lj;
        const bool inb = (gi >= 0) && (gi < H) && (gj >= 0) && (gj < W);
        const int cg = min(max(gi, 0), H - 1) * W + min(max(gj, 0), W - 1);
        // 6 unconditional loads (L2/HBM latency overlapped across rounds)
        const float v0 = xn[cg];
        const float v1 = xn[planeHW + cg];
        const float v2 = xn[2 * planeHW + cg];
        const float yv = yn[cg];
        const float m0 = msn[cg];
        const float m1 = mdn[cg];
        float4 P = make_float4(0.f, 0.f, 0.f, 0.f);
        float2 M = make_float2(0.f, 0.f);
        if (inb) {
            P = make_float4(v0, v1, v2, 1.0f / (1.0f + __expf(-yv)));
            M = make_float2(binarize(m0), binarize(m1));
        }
        if (act) { sP[li][lj] = P; sM[li][lj] = M; }
    }
    __syncthreads();

    const int ci = threadIdx.y + RADIUS, cj = threadIdx.x + RADIUS;
    const int gi = ti0 + threadIdx.y,    gj = tj0 + threadIdx.x;
    const bool valid = (gi < H && gj < W);

    float lsum = 0.0f, mdb = 0.0f;
    if (valid) {
        const float4 C  = sP[ci][cj];
        const float2 Mc = sM[ci][cj];
        const float  sc   = C.w;
        const float  c1m2 = 1.0f - 2.0f * sc;   // (1-sim) = fma(a, 1-2b, b)
        mdb = Mc.y;

        float lsum0 = 0.0f, lsum1 = 0.0f;       // split dependency chain
        #pragma unroll
        for (int k = 0; k < NOFF; ++k) {
            int di, dj;   // constant-folded under full unroll
            if (k < 5) { di = 0; dj = k + 1; }
            else       { di = (k - 5) / DIAM + 1; dj = (k - 5) % DIAM - RADIUS; }
            const float4 P = sP[ci + di][cj + dj];
            const float2 M = sM[ci + di][cj + dj];
            float d0 = P.x - C.x, d1 = P.y - C.y, d2 = P.z - C.z;
            float u  = fmaf(d2, d2, fmaf(d1, d1, d0 * d0));
            float e  = __expf(-50.0f * u);
            float w  = fmaf(WT.c1[k], e, WT.c2[k]);    // literal weights, no LDS
            float oms = fmaf(P.w, c1m2, sc);           // 1 - sim
            float pm  = fmaf(Mc.x, M.y, M.x * Mc.y);   // ms_c*md_q + ms_q*md_c
            if (k & 1) lsum1 = fmaf(w * oms, pm, lsum1);
            else       lsum0 = fmaf(w * oms, pm, lsum0);
        }
        lsum = lsum0 + lsum1;
    }

    // block reduction: wave shuffle then 4 partials in LDS
    float a = lsum, b = mdb;
    #pragma unroll
    for (int off = 32; off > 0; off >>= 1) {
        a += __shfl_down(a, off, 64);
        b += __shfl_down(b, off, 64);
    }
    const int wave = tid >> 6, lane = tid & 63;
    if (lane == 0) { wRedA[wave] = a; wRedB[wave] = b; }
    __syncthreads();
    if (tid == 0) {
        float t1 = wRedA[0] + wRedA[1] + wRedA[2] + wRedA[3];
        float t2 = wRedB[0] + wRedB[1] + wRedB[2] + wRedB[3];
        int bid = (blockIdx.z * gridDim.y + blockIdx.y) * gridDim.x + blockIdx.x;
        partial[bid] = make_float2(t1, t2);   // plain store: no init needed
    }
}

__global__ __launch_bounds__(256) void crf_final(
    const float2* __restrict__ partial, int G, float* __restrict__ out)
{
    __shared__ float wRedA[4], wRedB[4];
    float a = 0.f, b = 0.f;
    for (int i = threadIdx.x; i < G; i += 256) {
        float2 p = partial[i];
        a += p.x; b += p.y;
    }
    #pragma unroll
    for (int off = 32; off > 0; off >>= 1) {
        a += __shfl_down(a, off, 64);
        b += __shfl_down(b, off, 64);
    }
    const int wave = threadIdx.x >> 6, lane = threadIdx.x & 63;
    if (lane == 0) { wRedA[wave] = a; wRedB[wave] = b; }
    __syncthreads();
    if (threadIdx.x == 0) {
        double num   = (double)wRedA[0] + wRedA[1] + wRedA[2] + wRedA[3];
        double denom = (double)wRedB[0] + wRedB[1] + wRedB[2] + wRedB[3];
        if (denom < 1.0) denom = 1.0;
        out[0] = (float)(num / denom);
    }
}

extern "C" void kernel_launch(void* const* d_in, const int* in_sizes, int n_in,
                              void* d_out, int out_size, void* d_ws, size_t ws_size,
                              hipStream_t stream) {
    const float* x  = (const float*)d_in[0];
    const float* yv = (const float*)d_in[1];
    const float* ms = (const float*)d_in[2];
    const float* md = (const float*)d_in[3];
    float* out      = (float*)d_out;
    float2* partial = (float2*)d_ws;

    const int H = 256, W = 256;
    const int N = in_sizes[1] / (H * W);  // y is [N,H,W]

    dim3 block(TILE, TILE);
    dim3 grid((W + TILE - 1) / TILE, (H + TILE - 1) / TILE, N);
    const int G = grid.x * grid.y * grid.z;

    hipLaunchKernelGGL(crf_main, grid, block, 0, stream, x, yv, ms, md, partial, H, W);
    hipLaunchKernelGGL(crf_final, dim3(1), dim3(256), 0, stream, partial, G, out);
}